// Round 1
// baseline (2863.314 us; speedup 1.0000x reference)
//
#include <hip/hip_runtime.h>

// ---------------- problem constants (fixed by setup_inputs) ----------------
constexpr int kH  = 48;
constexpr int kW  = 160;
constexpr int kP  = 7680;   // kH*kW
constexpr int kC  = 128;
constexpr int kNB = 64;
constexpr int kNH = 8;
constexpr int kNL = 6;

// workspace layout (in floats)
constexpr long long OFF_F1T = 0;
constexpr long long OFF_F2T = 983040;
constexpr long long OFF_F2  = 1966080;                 // F2hat f32 [b][pix][c]
constexpr long long OFF_MU  = OFF_F2 + 62914560LL;     // 64880640
constexpr long long OFF_SIG = OFF_MU + 491520LL;       // 65372160
constexpr long long OFF_WTS = OFF_SIG + 491520LL;      // 65863680
// per-layer folded weight block (element offsets, elements are 4 B):
constexpr int WSA2 = 0;        // [cp][d] u32 (bf16x2 along c) 64*128
constexpr int WQ2  = 8192;     // [cp][d]
constexpr int WK2  = 16384;    // [d][cp]  (row-major for u-phase)
constexpr int WV2  = 24576;    // [cp][d]
constexpr int WO2  = 32768;    // [cp][d]
constexpr int BSA  = 40960;    // f32 [128]
constexpr int BQ   = 41088;
constexpr int BK   = 41216;
constexpr int BV   = 41344;
constexpr int WTS_STRIDE = 41472;

// d_out regions (floats)
constexpr long long OUT_ATT  = 0;         // (1,48,160,64)
constexpr long long OUT_MASK = 491520;    // (64,1,48,160)
constexpr long long OUT_LC   = 983040;    // (1,48,160)
constexpr long long OUT_SSIM = 990720;    // (1,64,48,160)

// ---------------- helpers ----------------
__device__ __forceinline__ float bf_lo(unsigned u) { return __uint_as_float(u << 16); }
__device__ __forceinline__ float bf_hi(unsigned u) { return __uint_as_float(u & 0xffff0000u); }
__device__ __forceinline__ unsigned pack_bf16(float a, float b) {
  unsigned ua = __float_as_uint(a), ub = __float_as_uint(b);
  unsigned ra = (ua + 0x7fffu + ((ua >> 16) & 1u)) >> 16;
  unsigned rb = (ub + 0x7fffu + ((ub >> 16) & 1u)) & 0xffff0000u;
  return (ra & 0xffffu) | rb;
}

// ---------------- kernel 1: NCHW -> [pix][c] transpose of feat1/feat2 ----------------
__global__ void k_transpose(const float* __restrict__ feat1, const float* __restrict__ feat2,
                            float* __restrict__ f1t, float* __restrict__ f2t) {
  int idx = blockIdx.x * 256 + threadIdx.x;  // < 983040
  int pix = idx >> 7, c = idx & 127;
  f1t[idx] = feat1[c * kP + pix];
  f2t[idx] = feat2[c * kP + pix];
}

// ---------------- kernel 2: fold LN gamma/beta + combine SA Wo@Wv, pack bf16 ----------------
__device__ __forceinline__ float redsum128(float v, float* red2) {
#pragma unroll
  for (int off = 32; off > 0; off >>= 1) v += __shfl_xor(v, off);
  int t = threadIdx.x;
  if ((t & 63) == 0) red2[t >> 6] = v;
  __syncthreads();
  float r = red2[0] + red2[1];
  __syncthreads();
  return r;
}

__global__ __launch_bounds__(128) void k_fold(
    const float* __restrict__ saw_, const float* __restrict__ sab_,
    const float* __restrict__ sow_, const float* __restrict__ sob_,
    const float* __restrict__ slg_, const float* __restrict__ slb_,
    const float* __restrict__ caw_, const float* __restrict__ cab_,
    const float* __restrict__ clg_, const float* __restrict__ clb_,
    const float* __restrict__ cow_, float* __restrict__ wts) {
  int i = blockIdx.x >> 7, d = blockIdx.x & 127, c = threadIdx.x;
  const float* saw = saw_ + (long long)i * 384 * kC;
  const float* sab = sab_ + i * 384;
  const float* sow = sow_ + i * kC * kC;
  const float* sob = sob_ + i * kC;
  const float* slg = slg_ + i * kC;
  const float* slb = slb_ + i * kC;
  const float* caw = caw_ + (long long)i * 384 * kC;
  const float* cab = cab_ + i * 384;
  const float* clg = clg_ + i * kC;
  const float* clb = clb_ + i * kC;
  const float* cow = cow_ + i * kC * kC;
  float* WL = wts + (long long)i * WTS_STRIDE;
  __shared__ float tmp[kC];
  __shared__ float red2[2];

  // ---- SA: Wsa_pre = Wo_sa @ Wv_sa, fold ln gamma/beta ----
  float acc = 0.f;
  for (int m = 0; m < kC; m++) acc += sow[d * kC + m] * saw[(256 + m) * kC + c];
  float t1 = redsum128(acc * slb[c] + sow[d * kC + c] * sab[256 + c], red2);
  if (c == 0) WL[BSA + d] = t1 + sob[d];
  tmp[c] = acc * slg[c];
  __syncthreads();
  if (c < 64) ((unsigned*)(WL + WSA2))[c * kC + d] = pack_bf16(tmp[2 * c], tmp[2 * c + 1]);
  __syncthreads();

  // ---- Q (x0.25 fold) ----
  float wq = caw[d * kC + c];
  float t2 = redsum128(wq * clb[c], red2);
  if (c == 0) WL[BQ + d] = 0.25f * (t2 + cab[d]);
  tmp[c] = 0.25f * wq * clg[c];
  __syncthreads();
  if (c < 64) ((unsigned*)(WL + WQ2))[c * kC + d] = pack_bf16(tmp[2 * c], tmp[2 * c + 1]);
  __syncthreads();

  // ---- K (row-major for u-phase) ----
  float wk = caw[(kC + d) * kC + c];
  float t3 = redsum128(wk * clb[c], red2);
  if (c == 0) WL[BK + d] = t3 + cab[kC + d];
  tmp[c] = wk * clg[c];
  __syncthreads();
  if (c < 64) ((unsigned*)(WL + WK2))[d * 64 + c] = pack_bf16(tmp[2 * c], tmp[2 * c + 1]);
  __syncthreads();

  // ---- V ----
  float wv = caw[(2 * kC + d) * kC + c];
  float t4 = redsum128(wv * clb[c], red2);
  if (c == 0) WL[BV + d] = t4 + cab[2 * kC + d];
  tmp[c] = wv * clg[c];
  __syncthreads();
  if (c < 64) ((unsigned*)(WL + WV2))[c * kC + d] = pack_bf16(tmp[2 * c], tmp[2 * c + 1]);
  __syncthreads();

  // ---- O (no fold, just pack) ----
  tmp[c] = cow[d * kC + c];
  __syncthreads();
  if (c < 64) ((unsigned*)(WL + WO2))[c * kC + d] = pack_bf16(tmp[2 * c], tmp[2 * c + 1]);
}

// ---------------- kernel 3: bilinear warp + per-(bin,pixel) LN stats + nearest mask ----------------
__global__ __launch_bounds__(256) void k_warp(const float* __restrict__ f2t,
                                              const float* __restrict__ coords,
                                              float* __restrict__ F2, float* __restrict__ mu,
                                              float* __restrict__ sig, float* __restrict__ maskout) {
  int wave = threadIdx.x >> 6, lane = threadIdx.x & 63;
  int pix = blockIdx.x * 4 + wave;
  int b = blockIdx.y;
  long long bp = (long long)b * kP + pix;
  float cx = coords[bp * 2], cy = coords[bp * 2 + 1];
  cx = (cx < -1.f) ? -2.f : cx;
  cx = (cx > 1.f) ? 2.f : cx;
  cy = (cy < -1.f) ? -2.f : cy;
  cy = (cy > 1.f) ? 2.f : cy;
  float gx = (cx + 1.f) * 0.5f * (float)(kW - 1);
  float gy = (cy + 1.f) * 0.5f * (float)(kH - 1);
  float x0f = floorf(gx), y0f = floorf(gy);
  float wx = gx - x0f, wy = gy - y0f;
  int x0 = (int)x0f, y0 = (int)y0f;
  int x1 = x0 + 1, y1 = y0 + 1;
  float vx0 = (x0 >= 0 && x0 < kW) ? 1.f : 0.f;
  float vx1 = (x1 >= 0 && x1 < kW) ? 1.f : 0.f;
  float vy0 = (y0 >= 0 && y0 < kH) ? 1.f : 0.f;
  float vy1 = (y1 >= 0 && y1 < kH) ? 1.f : 0.f;
  int x0c = min(max(x0, 0), kW - 1), x1c = min(max(x1, 0), kW - 1);
  int y0c = min(max(y0, 0), kH - 1), y1c = min(max(y1, 0), kH - 1);
  float w00 = (1.f - wy) * (1.f - wx) * vx0 * vy0;
  float w01 = (1.f - wy) * wx * vx1 * vy0;
  float w10 = wy * (1.f - wx) * vx0 * vy1;
  float w11 = wy * wx * vx1 * vy1;
  const float2* r00 = (const float2*)(f2t + (y0c * kW + x0c) * kC);
  const float2* r01 = (const float2*)(f2t + (y0c * kW + x1c) * kC);
  const float2* r10 = (const float2*)(f2t + (y1c * kW + x0c) * kC);
  const float2* r11 = (const float2*)(f2t + (y1c * kW + x1c) * kC);
  float2 g00 = r00[lane], g01 = r01[lane], g10 = r10[lane], g11 = r11[lane];
  float v0 = w00 * g00.x + w01 * g01.x + w10 * g10.x + w11 * g11.x;
  float v1 = w00 * g00.y + w01 * g01.y + w10 * g10.y + w11 * g11.y;
  float s = v0 + v1, s2 = v0 * v0 + v1 * v1;
#pragma unroll
  for (int off = 32; off > 0; off >>= 1) {
    s += __shfl_xor(s, off);
    s2 += __shfl_xor(s2, off);
  }
  float m = s * (1.f / 128.f);
  float var = s2 * (1.f / 128.f) - m * m;
  float rs = rsqrtf(var + 1e-5f);
  float2 o;
  o.x = (v0 - m) * rs;
  o.y = (v1 - m) * rs;
  ((float2*)(F2 + bp * kC))[lane] = o;
  if (lane == 0) {
    mu[bp] = m;
    sig[bp] = sqrtf(var + 1e-5f);
    int xi = (int)rintf(gx), yi = (int)rintf(gy);
    maskout[bp] = (xi >= 0 && xi < kW && yi >= 0 && yi < kH) ? 1.f : 0.f;
  }
}

// ---------------- kernel 4: SSIM volume (reflect-pad 3x3, mean over channels) ----------------
__global__ __launch_bounds__(256) void k_ssim(const float* __restrict__ f1t,
                                              const float* __restrict__ F2,
                                              const float* __restrict__ mu,
                                              const float* __restrict__ sig,
                                              float* __restrict__ ssimout) {
  int wave = threadIdx.x >> 6, lane = threadIdx.x & 63;
  int pix = blockIdx.x * 4 + wave;
  int b = blockIdx.y;
  int y = pix / kW, x = pix - y * kW;
  float sx0 = 0, sx1 = 0, sxx0 = 0, sxx1 = 0;
  float sw0 = 0, sw1 = 0, sww0 = 0, sww1 = 0, sxw0 = 0, sxw1 = 0;
#pragma unroll
  for (int dy = -1; dy <= 1; dy++) {
    int ry = y + dy;
    ry = (ry < 0) ? -ry : ((ry >= kH) ? (2 * kH - 2 - ry) : ry);
#pragma unroll
    for (int dx = -1; dx <= 1; dx++) {
      int rx = x + dx;
      rx = (rx < 0) ? -rx : ((rx >= kW) ? (2 * kW - 2 - rx) : rx);
      int rp = ry * kW + rx;
      float2 xv = ((const float2*)(f1t + rp * kC))[lane];
      long long nbp = (long long)b * kP + rp;
      float2 fv = ((const float2*)(F2 + nbp * kC))[lane];
      float m_ = mu[nbp], s_ = sig[nbp];
      float wv0 = fv.x * s_ + m_, wv1 = fv.y * s_ + m_;
      sx0 += xv.x; sxx0 += xv.x * xv.x; sw0 += wv0; sww0 += wv0 * wv0; sxw0 += xv.x * wv0;
      sx1 += xv.y; sxx1 += xv.y * xv.y; sw1 += wv1; sww1 += wv1 * wv1; sxw1 += xv.y * wv1;
    }
  }
  const float inv9 = 1.f / 9.f;
  float mx = sx0 * inv9, my = sw0 * inv9;
  float vx = sxx0 * inv9 - mx * mx, vy = sww0 * inv9 - my * my, vxy = sxw0 * inv9 - mx * my;
  float num = (2.f * mx * my + 1e-4f) * (2.f * vxy + 9e-4f);
  float den = (mx * mx + my * my + 1e-4f) * (vx + vy + 9e-4f);
  float val0 = fminf(fmaxf((1.f - num / den) * 0.5f, 0.f), 1.f);
  mx = sx1 * inv9; my = sw1 * inv9;
  vx = sxx1 * inv9 - mx * mx; vy = sww1 * inv9 - my * my; vxy = sxw1 * inv9 - mx * my;
  num = (2.f * mx * my + 1e-4f) * (2.f * vxy + 9e-4f);
  den = (mx * mx + my * my + 1e-4f) * (vx + vy + 9e-4f);
  float val1 = fminf(fmaxf((1.f - num / den) * 0.5f, 0.f), 1.f);
  float t = val0 + val1;
#pragma unroll
  for (int off = 32; off > 0; off >>= 1) t += __shfl_xor(t, off);
  if (lane == 0) ssimout[(long long)b * kP + pix] = t * (1.f / 128.f);
}

// ---------------- kernel 5: argmin over bins -> lowest_cost ----------------
__global__ __launch_bounds__(256) void k_argmin(const float* __restrict__ ssim,
                                                float* __restrict__ lc) {
  int pix = blockIdx.x * 256 + threadIdx.x;  // 7680 exact
  float best = ssim[pix];
  int bi = 0;
  for (int b = 1; b < kNB; b++) {
    float v = ssim[b * kP + pix];
    if (v < best) { best = v; bi = b; }
  }
  float depth = expf(-0.69314718f + (5.2983174f * (float)bi) / 63.0f);
  lc[pix] = 1.f / depth;
}

// ---------------- kernel 6: fused 6-layer transformer, 2 pixels / block ----------------
__device__ __forceinline__ void gemm2(const float* __restrict__ in, const unsigned* __restrict__ W2,
                                      const float* __restrict__ bias, float* out, float* Xacc,
                                      float* red, int tid, bool addX) {
  int d = tid & 127, half = tid >> 7;
  float a0 = 0.f, a1 = 0.f;
#pragma unroll
  for (int j = 0; j < 32; j++) {
    int cp = half * 32 + j;
    unsigned w2 = W2[cp * kC + d];
    float w0 = bf_lo(w2), w1 = bf_hi(w2);
    float2 xa = ((const float2*)in)[2 * cp];
    float2 xb = ((const float2*)in)[2 * cp + 1];
    a0 += w0 * xa.x + w1 * xb.x;
    a1 += w0 * xa.y + w1 * xb.y;
  }
  if (half) ((float2*)red)[d] = make_float2(a0, a1);
  __syncthreads();
  if (!half) {
    float2 r = ((float2*)red)[d];
    a0 += r.x + bias[d];
    a1 += r.y + bias[d];
    if (addX) {
      Xacc[0 * kC + d] += a0;
      Xacc[1 * kC + d] += a1;
    } else {
      ((float2*)out)[d] = make_float2(a0, a1);
    }
  }
}

__global__ __launch_bounds__(256) void k_attn(const float* __restrict__ f1t,
                                              const float* __restrict__ F2g,
                                              const float* __restrict__ wts,
                                              const float* __restrict__ cab_out,
                                              float* __restrict__ attn_out) {
  __shared__ __align__(16) unsigned F2s[2 * 64 * 66];  // bf16x2, row stride 66 u32 (=132 bf16)
  __shared__ __align__(16) float Xs[2 * kC];
  __shared__ __align__(16) float xh[kC * 2];   // [c][p]
  __shared__ __align__(16) float qb[kC * 2];   // [c][p]
  __shared__ __align__(16) float ubuf[2 * kNH * kC];  // [p][h][c]
  __shared__ __align__(16) float chs[2 * kNH];
  __shared__ __align__(16) float ps[2 * 64 * 8];  // [p][b][h]
  __shared__ __align__(16) float wbar[2 * kNH * 132];
  __shared__ __align__(16) float red[kC * 2];
  __shared__ __align__(16) float rawp[2 * 2 * 64];

  int tid = threadIdx.x;
  int wave = tid >> 6, lane = tid & 63;
  int pw = wave >> 1, hh = wave & 1;  // pixel-in-block, head-half
  int pix0 = blockIdx.x * 2;

  // init X state
  {
    int c = tid & 127, p = tid >> 7;
    Xs[p * kC + c] = f1t[(pix0 + p) * kC + c];
  }
  // load F2hat (f32 global) -> bf16 LDS
  {
    int mypix = pix0 + pw;
    for (int b = hh * 32; b < hh * 32 + 32; ++b) {
      float2 v = ((const float2*)(F2g + ((long long)b * kP + mypix) * kC))[lane];
      F2s[(pw * 64 + b) * 66 + lane] = pack_bf16(v.x, v.y);
    }
  }
  __syncthreads();

  for (int l = 0; l < kNL; ++l) {
    const float* WL = wts + (long long)l * WTS_STRIDE;

    // ---- LN (SA) ----
    {
      float2 xv = ((const float2*)(Xs + pw * kC))[lane];
      float s = xv.x + xv.y, s2 = xv.x * xv.x + xv.y * xv.y;
#pragma unroll
      for (int off = 32; off > 0; off >>= 1) {
        s += __shfl_xor(s, off);
        s2 += __shfl_xor(s2, off);
      }
      float m = s * (1.f / 128.f), var = s2 * (1.f / 128.f) - m * m;
      float rs = rsqrtf(var + 1e-5f);
      if (hh == 0) {
        xh[(2 * lane) * 2 + pw] = (xv.x - m) * rs;
        xh[(2 * lane + 1) * 2 + pw] = (xv.y - m) * rs;
      }
    }
    __syncthreads();
    // ---- SA: X += xhat @ Wsa'^T + bsa' ----
    gemm2(xh, (const unsigned*)(WL + WSA2), WL + BSA, nullptr, Xs, red, tid, true);
    __syncthreads();
    // ---- LN (CA) ----
    {
      float2 xv = ((const float2*)(Xs + pw * kC))[lane];
      float s = xv.x + xv.y, s2 = xv.x * xv.x + xv.y * xv.y;
#pragma unroll
      for (int off = 32; off > 0; off >>= 1) {
        s += __shfl_xor(s, off);
        s2 += __shfl_xor(s2, off);
      }
      float m = s * (1.f / 128.f), var = s2 * (1.f / 128.f) - m * m;
      float rs = rsqrtf(var + 1e-5f);
      if (hh == 0) {
        xh[(2 * lane) * 2 + pw] = (xv.x - m) * rs;
        xh[(2 * lane + 1) * 2 + pw] = (xv.y - m) * rs;
      }
    }
    __syncthreads();
    // ---- Q: q = xhat @ Wq''^T + bq'' ----
    gemm2(xh, (const unsigned*)(WL + WQ2), WL + BQ, qb, nullptr, red, tid, false);
    __syncthreads();
    // ---- U: u[p][h][c] = sum_o q[p][h*16+o] * Wk'[h*16+o][c] ----
    {
      int ccp = tid & 63, hg = tid >> 6;
      const unsigned* WK2p = (const unsigned*)(WL + WK2);
#pragma unroll
      for (int hi = 0; hi < 2; ++hi) {
        int h = hg * 2 + hi;
        float a00 = 0, a01 = 0, a10 = 0, a11 = 0;
#pragma unroll
        for (int o = 0; o < 16; o++) {
          unsigned w2 = WK2p[(h * 16 + o) * 64 + ccp];
          float w0 = bf_lo(w2), w1 = bf_hi(w2);
          float2 qv = ((const float2*)qb)[h * 16 + o];
          a00 += w0 * qv.x; a01 += w0 * qv.y;
          a10 += w1 * qv.x; a11 += w1 * qv.y;
        }
        ubuf[(0 * kNH + h) * kC + 2 * ccp] = a00;
        ubuf[(0 * kNH + h) * kC + 2 * ccp + 1] = a10;
        ubuf[(1 * kNH + h) * kC + 2 * ccp] = a01;
        ubuf[(1 * kNH + h) * kC + 2 * ccp + 1] = a11;
      }
      if (l == kNL - 1 && tid < 16) {
        int p = tid >> 3, h = tid & 7;
        float a = 0.f;
        for (int o = 0; o < 16; o++) a += qb[(h * 16 + o) * 2 + p] * WL[BK + h * 16 + o];
        chs[p * kNH + h] = a;
      }
    }
    __syncthreads();
    // ---- scores + softmax (wave = (pixel pw, heads hh*4..hh*4+3), lane = bin) ----
    float sc[4] = {0.f, 0.f, 0.f, 0.f};
    {
      const unsigned* f2row = &F2s[(pw * 64 + lane) * 66];
#pragma unroll 4
      for (int cb = 0; cb < kC; cb += 4) {
        uint2 f2p = *(const uint2*)(f2row + (cb >> 1));
        float f0 = bf_lo(f2p.x), f1v = bf_hi(f2p.x), f2v = bf_lo(f2p.y), f3v = bf_hi(f2p.y);
#pragma unroll
        for (int k = 0; k < 4; k++) {
          int h = hh * 4 + k;
          float4 uv = *(const float4*)(&ubuf[(pw * kNH + h) * kC + cb]);
          sc[k] += uv.x * f0 + uv.y * f1v + uv.z * f2v + uv.w * f3v;
        }
      }
    }
    float pv[4];
#pragma unroll
    for (int k = 0; k < 4; k++) {
      float mx = sc[k];
#pragma unroll
      for (int off = 32; off > 0; off >>= 1) mx = fmaxf(mx, __shfl_xor(mx, off));
      float e = expf(sc[k] - mx);
      float sm = e;
#pragma unroll
      for (int off = 32; off > 0; off >>= 1) sm += __shfl_xor(sm, off);
      pv[k] = e / sm;
    }
    *((float4*)(&ps[(pw * 64 + lane) * 8 + hh * 4])) = make_float4(pv[0], pv[1], pv[2], pv[3]);
    if (l == kNL - 1) {
      float r = sc[0] + sc[1] + sc[2] + sc[3] + chs[pw * kNH + hh * 4] + chs[pw * kNH + hh * 4 + 1] +
                chs[pw * kNH + hh * 4 + 2] + chs[pw * kNH + hh * 4 + 3];
      rawp[(pw * 2 + hh) * 64 + lane] = r;
      __syncthreads();
      if (hh == 0)
        attn_out[(long long)(pix0 + pw) * 64 + lane] =
            rawp[(pw * 2) * 64 + lane] + rawp[(pw * 2 + 1) * 64 + lane];
      break;
    }
    __syncthreads();
    // ---- wbar (wave = (pixel pw, heads hh*4..), lane = channel-pair) ----
    {
      float wa0x = 0, wa0y = 0, wa1x = 0, wa1y = 0, wa2x = 0, wa2y = 0, wa3x = 0, wa3y = 0;
#pragma unroll 8
      for (int b = 0; b < 64; b++) {
        unsigned f2p = F2s[(pw * 64 + b) * 66 + lane];
        float f0 = bf_lo(f2p), f1v = bf_hi(f2p);
        float4 pr = *(const float4*)(&ps[(pw * 64 + b) * 8 + hh * 4]);
        wa0x += pr.x * f0; wa0y += pr.x * f1v;
        wa1x += pr.y * f0; wa1y += pr.y * f1v;
        wa2x += pr.z * f0; wa2y += pr.z * f1v;
        wa3x += pr.w * f0; wa3y += pr.w * f1v;
      }
      int h0 = hh * 4;
      wbar[(pw * kNH + h0) * 132 + 2 * lane] = wa0x;
      wbar[(pw * kNH + h0) * 132 + 2 * lane + 1] = wa0y;
      wbar[(pw * kNH + h0 + 1) * 132 + 2 * lane] = wa1x;
      wbar[(pw * kNH + h0 + 1) * 132 + 2 * lane + 1] = wa1y;
      wbar[(pw * kNH + h0 + 2) * 132 + 2 * lane] = wa2x;
      wbar[(pw * kNH + h0 + 2) * 132 + 2 * lane + 1] = wa2y;
      wbar[(pw * kNH + h0 + 3) * 132 + 2 * lane] = wa3x;
      wbar[(pw * kNH + h0 + 3) * 132 + 2 * lane + 1] = wa3y;
    }
    __syncthreads();
    // ---- AO: ao[p][d] = wbar[p][d>>4] . Wv'[d] + bv' ----
    {
      int d = tid & 127, half = tid >> 7;
      int h = d >> 4;
      const unsigned* wv2 = (const unsigned*)(WL + WV2);
      float a0 = 0.f, a1 = 0.f;
#pragma unroll
      for (int j = 0; j < 32; j++) {
        int cp = half * 32 + j;
        unsigned w2 = wv2[cp * kC + d];
        float w0 = bf_lo(w2), w1 = bf_hi(w2);
        a0 += w0 * wbar[(0 * kNH + h) * 132 + 2 * cp] + w1 * wbar[(0 * kNH + h) * 132 + 2 * cp + 1];
        a1 += w0 * wbar[(1 * kNH + h) * 132 + 2 * cp] + w1 * wbar[(1 * kNH + h) * 132 + 2 * cp + 1];
      }
      if (half) ((float2*)red)[d] = make_float2(a0, a1);
      __syncthreads();
      if (!half) {
        float2 r = ((float2*)red)[d];
        a0 += r.x + WL[BV + d];
        a1 += r.y + WL[BV + d];
        ((float2*)xh)[d] = make_float2(a0, a1);
      }
    }
    __syncthreads();
    // ---- O: X += ao @ Wo^T + bo ----
    gemm2(xh, (const unsigned*)(WL + WO2), cab_out + l * kC, nullptr, Xs, red, tid, true);
    __syncthreads();
  }
}

// ---------------- launch ----------------
extern "C" void kernel_launch(void* const* d_in, const int* in_sizes, int n_in, void* d_out,
                              int out_size, void* d_ws, size_t ws_size, hipStream_t stream) {
  (void)in_sizes; (void)n_in; (void)out_size; (void)ws_size;
  const float* feat1 = (const float*)d_in[0];
  const float* feat2 = (const float*)d_in[1];
  const float* coords = (const float*)d_in[2];
  const float* sa_in_w = (const float*)d_in[3];
  const float* sa_in_b = (const float*)d_in[4];
  const float* sa_out_w = (const float*)d_in[5];
  const float* sa_out_b = (const float*)d_in[6];
  const float* sa_ln_g = (const float*)d_in[7];
  const float* sa_ln_b = (const float*)d_in[8];
  const float* ca_in_w = (const float*)d_in[9];
  const float* ca_in_b = (const float*)d_in[10];
  const float* ca_out_w = (const float*)d_in[11];
  const float* ca_out_b = (const float*)d_in[12];
  const float* ca_ln_g = (const float*)d_in[13];
  const float* ca_ln_b = (const float*)d_in[14];

  float* out = (float*)d_out;
  float* ws = (float*)d_ws;
  float* f1t = ws + OFF_F1T;
  float* f2t = ws + OFF_F2T;
  float* F2 = ws + OFF_F2;
  float* mu = ws + OFF_MU;
  float* sig = ws + OFF_SIG;
  float* wts = ws + OFF_WTS;  // needs ws_size >= ~265 MB

  float* att = out + OUT_ATT;
  float* mask = out + OUT_MASK;
  float* lc = out + OUT_LC;
  float* ssim = out + OUT_SSIM;

  k_transpose<<<3840, 256, 0, stream>>>(feat1, feat2, f1t, f2t);
  k_fold<<<kNL * 128, 128, 0, stream>>>(sa_in_w, sa_in_b, sa_out_w, sa_out_b, sa_ln_g, sa_ln_b,
                                        ca_in_w, ca_in_b, ca_ln_g, ca_ln_b, ca_out_w, wts);
  dim3 g1(1920, 64);
  k_warp<<<g1, 256, 0, stream>>>(f2t, coords, F2, mu, sig, mask);
  k_ssim<<<g1, 256, 0, stream>>>(f1t, F2, mu, sig, ssim);
  k_argmin<<<30, 256, 0, stream>>>(ssim, lc);
  k_attn<<<3840, 256, 0, stream>>>(f1t, F2, wts, ca_out_b, att);
}

// Round 3
// 949.724 us; speedup vs baseline: 3.0149x; 3.0149x over previous
//
#include <hip/hip_runtime.h>

// ---------------- problem constants (fixed by setup_inputs) ----------------
constexpr int kH  = 48;
constexpr int kW  = 160;
constexpr int kP  = 7680;   // kH*kW
constexpr int kC  = 128;
constexpr int kNB = 64;
constexpr int kNH = 8;
constexpr int kNL = 6;

// workspace layout (in floats)
constexpr long long OFF_F1T = 0;
constexpr long long OFF_F2T = 983040;
constexpr long long OFF_F2  = 1966080;                 // F2hat f32 [b][pix][c]
constexpr long long OFF_MU  = OFF_F2 + 62914560LL;
constexpr long long OFF_SIG = OFF_MU + 491520LL;
constexpr long long OFF_WTS = OFF_SIG + 491520LL;
// per-layer folded weight block (element offsets, elements are 4 B):
// std matrices are f16 packed: [16 cchunk][128 d][4 u32]  (u32 = f16x2 along c)
// WKU: [8 h][128 c][8 u32]  (u32 = f16x2 along o)
constexpr int WSA2 = 0;
constexpr int WQ2  = 8192;
constexpr int WKU  = 16384;
constexpr int WV2  = 24576;
constexpr int WO2  = 32768;
constexpr int BSA  = 40960;    // f32 [128]
constexpr int BQ   = 41088;
constexpr int BK   = 41216;
constexpr int BV   = 41344;
constexpr int WTS_STRIDE = 41472;

// d_out regions (floats)
constexpr long long OUT_ATT  = 0;         // (1,48,160,64)
constexpr long long OUT_MASK = 491520;    // (64,1,48,160)
constexpr long long OUT_LC   = 983040;    // (1,48,160)
constexpr long long OUT_SSIM = 990720;    // (1,64,48,160)

// ---------------- helpers ----------------
typedef _Float16 h2v __attribute__((ext_vector_type(2)));
typedef __fp16 p2v __attribute__((ext_vector_type(2)));
typedef float f2v __attribute__((ext_vector_type(2)));
union U32H2 { unsigned u; h2v h; };
union U32P2 { unsigned u; p2v h; };

__device__ __forceinline__ float fdot2(unsigned a, unsigned b, float c) {
  U32H2 ua; ua.u = a; U32H2 ub; ub.u = b;
  return __builtin_amdgcn_fdot2(ua.h, ub.h, c, false);
}
__device__ __forceinline__ unsigned pkrtz(float a, float b) {
  U32P2 t; t.h = __builtin_amdgcn_cvt_pkrtz(a, b); return t.u;
}
__device__ __forceinline__ f2v h2f(unsigned u) {
  U32P2 t; t.u = u; f2v r; r.x = (float)t.h.x; r.y = (float)t.h.y; return r;
}
__device__ __forceinline__ unsigned short f2h(float x) {
  U32P2 t; t.h = __builtin_amdgcn_cvt_pkrtz(x, 0.f); return (unsigned short)(t.u & 0xffffu);
}
// compiler-order pin for wave-internal LDS producer->consumer (HW LDS is in-order per wave)
__device__ __forceinline__ void wb() {
  __asm__ __volatile__("" ::: "memory");
  __builtin_amdgcn_wave_barrier();
  __asm__ __volatile__("" ::: "memory");
}

// ---------------- kernel 1: NCHW -> [pix][c] transpose of feat1/feat2 ----------------
__global__ void k_transpose(const float* __restrict__ feat1, const float* __restrict__ feat2,
                            float* __restrict__ f1t, float* __restrict__ f2t) {
  int idx = blockIdx.x * 256 + threadIdx.x;  // < 983040
  int pix = idx >> 7, c = idx & 127;
  f1t[idx] = feat1[c * kP + pix];
  f2t[idx] = feat2[c * kP + pix];
}

// ---------------- kernel 2: fold LN gamma/beta + combine SA Wo@Wv, pack f16 ----------------
__device__ __forceinline__ float redsum128(float v, float* red2) {
#pragma unroll
  for (int off = 32; off > 0; off >>= 1) v += __shfl_xor(v, off);
  int t = threadIdx.x;
  if ((t & 63) == 0) red2[t >> 6] = v;
  __syncthreads();
  float r = red2[0] + red2[1];
  __syncthreads();
  return r;
}

__global__ __launch_bounds__(128) void k_fold(
    const float* __restrict__ saw_, const float* __restrict__ sab_,
    const float* __restrict__ sow_, const float* __restrict__ sob_,
    const float* __restrict__ slg_, const float* __restrict__ slb_,
    const float* __restrict__ caw_, const float* __restrict__ cab_,
    const float* __restrict__ clg_, const float* __restrict__ clb_,
    const float* __restrict__ cow_, float* __restrict__ wts) {
  int i = blockIdx.x >> 7, d = blockIdx.x & 127, c = threadIdx.x;
  const float* saw = saw_ + (long long)i * 384 * kC;
  const float* sab = sab_ + i * 384;
  const float* sow = sow_ + i * kC * kC;
  const float* sob = sob_ + i * kC;
  const float* slg = slg_ + i * kC;
  const float* slb = slb_ + i * kC;
  const float* caw = caw_ + (long long)i * 384 * kC;
  const float* cab = cab_ + i * 384;
  const float* clg = clg_ + i * kC;
  const float* clb = clb_ + i * kC;
  const float* cow = cow_ + i * kC * kC;
  float* WL = wts + (long long)i * WTS_STRIDE;
  __shared__ float red2[2];

  int jstd = (c >> 3) * 1024 + d * 8 + (c & 7);  // std matrix u16 index for (c,d)

  // ---- SA: Wsa_pre = Wo_sa @ Wv_sa, fold ln gamma/beta ----
  float acc = 0.f;
  for (int m = 0; m < kC; m++) acc += sow[d * kC + m] * saw[(256 + m) * kC + c];
  float t1 = redsum128(acc * slb[c] + sow[d * kC + c] * sab[256 + c], red2);
  if (c == 0) WL[BSA + d] = t1 + sob[d];
  ((unsigned short*)(WL + WSA2))[jstd] = f2h(acc * slg[c]);

  // ---- Q (x0.25 fold) ----
  float wq = caw[d * kC + c];
  float t2 = redsum128(wq * clb[c], red2);
  if (c == 0) WL[BQ + d] = 0.25f * (t2 + cab[d]);
  ((unsigned short*)(WL + WQ2))[jstd] = f2h(0.25f * wq * clg[c]);

  // ---- K -> WKU [h][c][o-pairs] ----
  float wk = caw[(kC + d) * kC + c];
  float t3 = redsum128(wk * clb[c], red2);
  if (c == 0) WL[BK + d] = t3 + cab[kC + d];
  {
    int h = d >> 4, o = d & 15;
    ((unsigned short*)(WL + WKU))[h * 2048 + c * 16 + o] = f2h(wk * clg[c]);
  }

  // ---- V ----
  float wv = caw[(2 * kC + d) * kC + c];
  float t4 = redsum128(wv * clb[c], red2);
  if (c == 0) WL[BV + d] = t4 + cab[2 * kC + d];
  ((unsigned short*)(WL + WV2))[jstd] = f2h(wv * clg[c]);

  // ---- O (no fold, just pack) ----
  ((unsigned short*)(WL + WO2))[jstd] = f2h(cow[d * kC + c]);
}

// ---------------- kernel 3: bilinear warp + per-(bin,pixel) LN stats + nearest mask ----------------
__global__ __launch_bounds__(256) void k_warp(const float* __restrict__ f2t,
                                              const float* __restrict__ coords,
                                              float* __restrict__ F2, float* __restrict__ mu,
                                              float* __restrict__ sig, float* __restrict__ maskout) {
  int wave = threadIdx.x >> 6, lane = threadIdx.x & 63;
  int pix = blockIdx.x * 4 + wave;
  int b = blockIdx.y;
  long long bp = (long long)b * kP + pix;
  float cx = coords[bp * 2], cy = coords[bp * 2 + 1];
  cx = (cx < -1.f) ? -2.f : cx;
  cx = (cx > 1.f) ? 2.f : cx;
  cy = (cy < -1.f) ? -2.f : cy;
  cy = (cy > 1.f) ? 2.f : cy;
  float gx = (cx + 1.f) * 0.5f * (float)(kW - 1);
  float gy = (cy + 1.f) * 0.5f * (float)(kH - 1);
  float x0f = floorf(gx), y0f = floorf(gy);
  float wx = gx - x0f, wy = gy - y0f;
  int x0 = (int)x0f, y0 = (int)y0f;
  int x1 = x0 + 1, y1 = y0 + 1;
  float vx0 = (x0 >= 0 && x0 < kW) ? 1.f : 0.f;
  float vx1 = (x1 >= 0 && x1 < kW) ? 1.f : 0.f;
  float vy0 = (y0 >= 0 && y0 < kH) ? 1.f : 0.f;
  float vy1 = (y1 >= 0 && y1 < kH) ? 1.f : 0.f;
  int x0c = min(max(x0, 0), kW - 1), x1c = min(max(x1, 0), kW - 1);
  int y0c = min(max(y0, 0), kH - 1), y1c = min(max(y1, 0), kH - 1);
  float w00 = (1.f - wy) * (1.f - wx) * vx0 * vy0;
  float w01 = (1.f - wy) * wx * vx1 * vy0;
  float w10 = wy * (1.f - wx) * vx0 * vy1;
  float w11 = wy * wx * vx1 * vy1;
  const float2* r00 = (const float2*)(f2t + (y0c * kW + x0c) * kC);
  const float2* r01 = (const float2*)(f2t + (y0c * kW + x1c) * kC);
  const float2* r10 = (const float2*)(f2t + (y1c * kW + x0c) * kC);
  const float2* r11 = (const float2*)(f2t + (y1c * kW + x1c) * kC);
  float2 g00 = r00[lane], g01 = r01[lane], g10 = r10[lane], g11 = r11[lane];
  float v0 = w00 * g00.x + w01 * g01.x + w10 * g10.x + w11 * g11.x;
  float v1 = w00 * g00.y + w01 * g01.y + w10 * g10.y + w11 * g11.y;
  float s = v0 + v1, s2 = v0 * v0 + v1 * v1;
#pragma unroll
  for (int off = 32; off > 0; off >>= 1) {
    s += __shfl_xor(s, off);
    s2 += __shfl_xor(s2, off);
  }
  float m = s * (1.f / 128.f);
  float var = s2 * (1.f / 128.f) - m * m;
  float rs = rsqrtf(var + 1e-5f);
  float2 o;
  o.x = (v0 - m) * rs;
  o.y = (v1 - m) * rs;
  ((float2*)(F2 + bp * kC))[lane] = o;
  if (lane == 0) {
    mu[bp] = m;
    sig[bp] = sqrtf(var + 1e-5f);
    int xi = (int)rintf(gx), yi = (int)rintf(gy);
    maskout[bp] = (xi >= 0 && xi < kW && yi >= 0 && yi < kH) ? 1.f : 0.f;
  }
}

// ---------------- kernel 4: SSIM volume (reflect-pad 3x3, mean over channels) ----------------
__global__ __launch_bounds__(256) void k_ssim(const float* __restrict__ f1t,
                                              const float* __restrict__ F2,
                                              const float* __restrict__ mu,
                                              const float* __restrict__ sig,
                                              float* __restrict__ ssimout) {
  int wave = threadIdx.x >> 6, lane = threadIdx.x & 63;
  int pix = blockIdx.x * 4 + wave;
  int b = blockIdx.y;
  int y = pix / kW, x = pix - y * kW;
  float sx0 = 0, sx1 = 0, sxx0 = 0, sxx1 = 0;
  float sw0 = 0, sw1 = 0, sww0 = 0, sww1 = 0, sxw0 = 0, sxw1 = 0;
#pragma unroll
  for (int dy = -1; dy <= 1; dy++) {
    int ry = y + dy;
    ry = (ry < 0) ? -ry : ((ry >= kH) ? (2 * kH - 2 - ry) : ry);
#pragma unroll
    for (int dx = -1; dx <= 1; dx++) {
      int rx = x + dx;
      rx = (rx < 0) ? -rx : ((rx >= kW) ? (2 * kW - 2 - rx) : rx);
      int rp = ry * kW + rx;
      float2 xv = ((const float2*)(f1t + rp * kC))[lane];
      long long nbp = (long long)b * kP + rp;
      float2 fv = ((const float2*)(F2 + nbp * kC))[lane];
      float m_ = mu[nbp], s_ = sig[nbp];
      float wv0 = fv.x * s_ + m_, wv1 = fv.y * s_ + m_;
      sx0 += xv.x; sxx0 += xv.x * xv.x; sw0 += wv0; sww0 += wv0 * wv0; sxw0 += xv.x * wv0;
      sx1 += xv.y; sxx1 += xv.y * xv.y; sw1 += wv1; sww1 += wv1 * wv1; sxw1 += xv.y * wv1;
    }
  }
  const float inv9 = 1.f / 9.f;
  float mx = sx0 * inv9, my = sw0 * inv9;
  float vx = sxx0 * inv9 - mx * mx, vy = sww0 * inv9 - my * my, vxy = sxw0 * inv9 - mx * my;
  float num = (2.f * mx * my + 1e-4f) * (2.f * vxy + 9e-4f);
  float den = (mx * mx + my * my + 1e-4f) * (vx + vy + 9e-4f);
  float val0 = fminf(fmaxf((1.f - num / den) * 0.5f, 0.f), 1.f);
  mx = sx1 * inv9; my = sw1 * inv9;
  vx = sxx1 * inv9 - mx * mx; vy = sww1 * inv9 - my * my; vxy = sxw1 * inv9 - mx * my;
  num = (2.f * mx * my + 1e-4f) * (2.f * vxy + 9e-4f);
  den = (mx * mx + my * my + 1e-4f) * (vx + vy + 9e-4f);
  float val1 = fminf(fmaxf((1.f - num / den) * 0.5f, 0.f), 1.f);
  float t = val0 + val1;
#pragma unroll
  for (int off = 32; off > 0; off >>= 1) t += __shfl_xor(t, off);
  if (lane == 0) ssimout[(long long)b * kP + pix] = t * (1.f / 128.f);
}

// ---------------- kernel 5: argmin over bins -> lowest_cost ----------------
__global__ __launch_bounds__(256) void k_argmin(const float* __restrict__ ssim,
                                                float* __restrict__ lc) {
  int pix = blockIdx.x * 256 + threadIdx.x;  // 7680 exact
  float best = ssim[pix];
  int bi = 0;
  for (int b = 1; b < kNB; b++) {
    float v = ssim[b * kP + pix];
    if (v < best) { best = v; bi = b; }
  }
  float depth = expf(-0.69314718f + (5.2983174f * (float)bi) / 63.0f);
  lc[pix] = 1.f / depth;
}

// ---------------- kernel 6: fused 6-layer transformer, 1 pixel / wave, no block barriers ----
// LDS 18688 B/wave -> 8 waves/CU. All cross-lane data goes through wave-private LDS
// (in-order per wave) or shuffles; f16 activations/weights with v_dot2_f32_f16.

__device__ __forceinline__ f2v gemmW(int l, const unsigned* __restrict__ inb,
                                     const unsigned* __restrict__ W, float b0, float b1) {
  float a0 = b0, a1 = b1;
  const unsigned* wp = W + l * 8;  // d = 2l (then +4 for d = 2l+1)
#pragma unroll
  for (int j = 0; j < 16; ++j) {
    uint4 in4 = *(const uint4*)(inb + 4 * j);   // LDS broadcast: 8 channels (f16x2 x4)
    uint4 wa = *(const uint4*)(wp + j * 512);
    uint4 wbv = *(const uint4*)(wp + j * 512 + 4);
    a0 = fdot2(in4.x, wa.x, a0);  a0 = fdot2(in4.y, wa.y, a0);
    a0 = fdot2(in4.z, wa.z, a0);  a0 = fdot2(in4.w, wa.w, a0);
    a1 = fdot2(in4.x, wbv.x, a1); a1 = fdot2(in4.y, wbv.y, a1);
    a1 = fdot2(in4.z, wbv.z, a1); a1 = fdot2(in4.w, wbv.w, a1);
  }
  f2v r; r.x = a0; r.y = a1; return r;
}

__device__ __forceinline__ void ln_store(int l, f2v X, unsigned* xhq) {
  float s = X.x + X.y, s2 = X.x * X.x + X.y * X.y;
#pragma unroll
  for (int o = 32; o > 0; o >>= 1) { s += __shfl_xor(s, o); s2 += __shfl_xor(s2, o); }
  float m = s * 0.0078125f;
  float var = s2 * 0.0078125f - m * m;
  float rs = rsqrtf(var + 1e-5f);
  xhq[l] = pkrtz((X.x - m) * rs, (X.y - m) * rs);
}

__global__ __launch_bounds__(64) void k_attn(const float* __restrict__ F2g,
                                             const float* __restrict__ f1t,
                                             const float* __restrict__ wts,
                                             const float* __restrict__ cab_out,
                                             float* __restrict__ attn_out) {
  // F2s: [64 bins][64 u32 f16x2], XOR-swizzled: phys col = col ^ (4*(bin&15))
  __shared__ __align__(16) unsigned F2s[64 * 64];
  // upb: u (f16x2 [8h][64]) -> p (f32 [64b][8h]) -> wbar packed ([8h][64], col ^= 4*h)
  __shared__ __align__(16) unsigned upb[512];
  __shared__ __align__(16) unsigned xhq[64];  // xhat, later q (f16x2 c-pairs)

  const int l = threadIdx.x;
  const int pix = blockIdx.x;

  // ---- load this pixel's F2hat (f32 global) -> f16x2 swizzled LDS ----
  {
#pragma unroll 4
    for (int r = 0; r < 64; ++r) {
      float2 v = *(const float2*)(F2g + ((long long)r * kP + pix) * kC + 2 * l);
      F2s[r * 64 + (l ^ (4 * (r & 15)))] = pkrtz(v.x, v.y);
    }
  }
  f2v X;
  { float2 xv = ((const float2*)(f1t + (long long)pix * kC))[l]; X.x = xv.x; X.y = xv.y; }
  wb();

  float chsum = 0.f;
  float* pf = (float*)upb;

  for (int ly = 0; ly < kNL; ++ly) {
    const float* WL = wts + (long long)ly * WTS_STRIDE;

    // ---- LN(SA) -> xhq ; SA gemm ; residual ----
    ln_store(l, X, xhq);
    wb();
    {
      float2 bv = ((const float2*)(WL + BSA))[l];
      f2v o = gemmW(l, xhq, (const unsigned*)(WL + WSA2), bv.x, bv.y);
      X += o;
    }
    wb();
    // ---- LN(CA) -> xhq ; Q gemm ----
    ln_store(l, X, xhq);
    wb();
    f2v q;
    {
      float2 bv = ((const float2*)(WL + BQ))[l];
      q = gemmW(l, xhq, (const unsigned*)(WL + WQ2), bv.x, bv.y);
    }
    if (ly == kNL - 1) {  // k-bias contribution to raw: full dot q.bk
      float2 bk = ((const float2*)(WL + BK))[l];
      float cp = q.x * bk.x + q.y * bk.y;
#pragma unroll
      for (int o = 32; o > 0; o >>= 1) cp += __shfl_xor(cp, o);
      chsum = cp;
    }
    xhq[l] = pkrtz(q.x, q.y);  // qpk (d-pairs == o-pairs)
    wb();

    // ---- U: u[h][c-pair l] = sum_o q[h*16+o] * Wk'[h*16+o][c] ----
    {
      const unsigned* KU = (const unsigned*)(WL + WKU);
#pragma unroll
      for (int h = 0; h < kNH; ++h) {
        uint4 q0 = *(const uint4*)(xhq + h * 8);      // o-pairs 0..3 (broadcast)
        uint4 q1 = *(const uint4*)(xhq + h * 8 + 4);  // o-pairs 4..7
        const unsigned* w0 = KU + (h * 128 + 2 * l) * 8;
        uint4 a0 = ((const uint4*)w0)[0], a1 = ((const uint4*)w0)[1];
        uint4 b0 = ((const uint4*)w0)[2], b1 = ((const uint4*)w0)[3];  // c = 2l+1
        float u0 = 0.f, u1 = 0.f;
        u0 = fdot2(q0.x, a0.x, u0); u0 = fdot2(q0.y, a0.y, u0);
        u0 = fdot2(q0.z, a0.z, u0); u0 = fdot2(q0.w, a0.w, u0);
        u0 = fdot2(q1.x, a1.x, u0); u0 = fdot2(q1.y, a1.y, u0);
        u0 = fdot2(q1.z, a1.z, u0); u0 = fdot2(q1.w, a1.w, u0);
        u1 = fdot2(q0.x, b0.x, u1); u1 = fdot2(q0.y, b0.y, u1);
        u1 = fdot2(q0.z, b0.z, u1); u1 = fdot2(q0.w, b0.w, u1);
        u1 = fdot2(q1.x, b1.x, u1); u1 = fdot2(q1.y, b1.y, u1);
        u1 = fdot2(q1.w, b1.w, u1); u1 = fdot2(q1.z, b1.z, u1);
        upb[h * 64 + l] = pkrtz(u0, u1);
      }
    }
    wb();

    // ---- scores: lane = bin; sc[h] = sum_c u[h][c]*F2[bin][c] ----
    float sc[8] = {0, 0, 0, 0, 0, 0, 0, 0};
    {
      const unsigned* f2row = F2s + l * 64;
      const int sw = 4 * (l & 15);
#pragma unroll 4
      for (int j = 0; j < 16; ++j) {
        uint4 fv = *(const uint4*)(f2row + ((4 * j) ^ sw));
#pragma unroll
        for (int h = 0; h < kNH; ++h) {
          uint4 uv = *(const uint4*)(upb + h * 64 + 4 * j);  // broadcast
          sc[h] = fdot2(fv.x, uv.x, sc[h]);
          sc[h] = fdot2(fv.y, uv.y, sc[h]);
          sc[h] = fdot2(fv.z, uv.z, sc[h]);
          sc[h] = fdot2(fv.w, uv.w, sc[h]);
        }
      }
    }
    if (ly == kNL - 1) {
      float r = sc[0] + sc[1] + sc[2] + sc[3] + sc[4] + sc[5] + sc[6] + sc[7] + chsum;
      attn_out[(long long)pix * 64 + l] = r;
      return;
    }
    wb();
    // ---- softmax over bins (cross-lane), p -> pf[bin][h] (overwrites u) ----
    {
      float pv[8];
#pragma unroll
      for (int h = 0; h < kNH; ++h) {
        float mx = sc[h];
#pragma unroll
        for (int o = 32; o > 0; o >>= 1) mx = fmaxf(mx, __shfl_xor(mx, o));
        float e = __expf(sc[h] - mx);
        float sm = e;
#pragma unroll
        for (int o = 32; o > 0; o >>= 1) sm += __shfl_xor(sm, o);
        pv[h] = e / sm;
      }
      *(float4*)(pf + l * 8) = make_float4(pv[0], pv[1], pv[2], pv[3]);
      *(float4*)(pf + l * 8 + 4) = make_float4(pv[4], pv[5], pv[6], pv[7]);
    }
    wb();
    // ---- wbar[h][c] = sum_b p[b][h]*F2[b][c]; lane owns 4 ch, half-wave owns 32 bins ----
    {
      const int half = l >> 5, lb = l & 31;
      f2v wA[8], wB[8];
#pragma unroll
      for (int h = 0; h < kNH; ++h) { wA[h] = (f2v)0.f; wB[h] = (f2v)0.f; }
#pragma unroll 2
      for (int t = 0; t < 32; ++t) {
        int b = half * 32 + t;
        uint2 fv = *(const uint2*)(F2s + b * 64 + ((2 * lb) ^ (4 * (b & 15))));
        f2v fA = h2f(fv.x), fB = h2f(fv.y);
        float4 pA = *(const float4*)(pf + b * 8);
        float4 pB = *(const float4*)(pf + b * 8 + 4);
        wA[0] += fA * pA.x; wB[0] += fB * pA.x;
        wA[1] += fA * pA.y; wB[1] += fB * pA.y;
        wA[2] += fA * pA.z; wB[2] += fB * pA.z;
        wA[3] += fA * pA.w; wB[3] += fB * pA.w;
        wA[4] += fA * pB.x; wB[4] += fB * pB.x;
        wA[5] += fA * pB.y; wB[5] += fB * pB.y;
        wA[6] += fA * pB.z; wB[6] += fB * pB.z;
        wA[7] += fA * pB.w; wB[7] += fB * pB.w;
      }
      // combine halves
#pragma unroll
      for (int h = 0; h < kNH; ++h) {
        wA[h].x += __shfl_xor(wA[h].x, 32);
        wA[h].y += __shfl_xor(wA[h].y, 32);
        wB[h].x += __shfl_xor(wB[h].x, 32);
        wB[h].y += __shfl_xor(wB[h].y, 32);
      }
      wb();
      // write packed wbar into upb ([8h][64], col swizzle ^ 4h); halves split h-ranges
#pragma unroll
      for (int hh = 0; hh < 4; ++hh) {
        int h = half * 4 + hh;
        uint2 pk;
        pk.x = pkrtz(wA[h].x, wA[h].y);
        pk.y = pkrtz(wB[h].x, wB[h].y);
        *(uint2*)(upb + h * 64 + ((2 * lb) ^ (4 * h))) = pk;
      }
    }
    wb();
    // ---- AO: ao[d] = wbar[h(d)] . Wv'[:,d] + bv ----
    {
      const int h = l >> 3;  // d=2l -> head
      const unsigned* wrow = upb + h * 64;
      const unsigned* WV = (const unsigned*)(WL + WV2) + l * 8;
      float2 bv = ((const float2*)(WL + BV))[l];
      float a0 = bv.x, a1 = bv.y;
      const int sw = 4 * h;
#pragma unroll
      for (int j = 0; j < 16; ++j) {
        uint4 in4 = *(const uint4*)(wrow + ((4 * j) ^ sw));
        uint4 wa = *(const uint4*)(WV + j * 512);
        uint4 wbv = *(const uint4*)(WV + j * 512 + 4);
        a0 = fdot2(in4.x, wa.x, a0);  a0 = fdot2(in4.y, wa.y, a0);
        a0 = fdot2(in4.z, wa.z, a0);  a0 = fdot2(in4.w, wa.w, a0);
        a1 = fdot2(in4.x, wbv.x, a1); a1 = fdot2(in4.y, wbv.y, a1);
        a1 = fdot2(in4.z, wbv.z, a1); a1 = fdot2(in4.w, wbv.w, a1);
      }
      xhq[l] = pkrtz(a0, a1);
    }
    wb();
    // ---- O: X += ao @ Wo^T + bo ----
    {
      float2 bv = ((const float2*)(cab_out + ly * kC))[l];
      f2v o = gemmW(l, xhq, (const unsigned*)(WL + WO2), bv.x, bv.y);
      X += o;
    }
    wb();
  }
}

// ---------------- launch ----------------
extern "C" void kernel_launch(void* const* d_in, const int* in_sizes, int n_in, void* d_out,
                              int out_size, void* d_ws, size_t ws_size, hipStream_t stream) {
  (void)in_sizes; (void)n_in; (void)out_size; (void)ws_size;
  const float* feat1 = (const float*)d_in[0];
  const float* feat2 = (const float*)d_in[1];
  const float* coords = (const float*)d_in[2];
  const float* sa_in_w = (const float*)d_in[3];
  const float* sa_in_b = (const float*)d_in[4];
  const float* sa_out_w = (const float*)d_in[5];
  const float* sa_out_b = (const float*)d_in[6];
  const float* sa_ln_g = (const float*)d_in[7];
  const float* sa_ln_b = (const float*)d_in[8];
  const float* ca_in_w = (const float*)d_in[9];
  const float* ca_in_b = (const float*)d_in[10];
  const float* ca_out_w = (const float*)d_in[11];
  const float* ca_out_b = (const float*)d_in[12];
  const float* ca_ln_g = (const float*)d_in[13];
  const float* ca_ln_b = (const float*)d_in[14];

  float* out = (float*)d_out;
  float* ws = (float*)d_ws;
  float* f1t = ws + OFF_F1T;
  float* f2t = ws + OFF_F2T;
  float* F2 = ws + OFF_F2;
  float* mu = ws + OFF_MU;
  float* sig = ws + OFF_SIG;
  float* wts = ws + OFF_WTS;

  float* att = out + OUT_ATT;
  float* mask = out + OUT_MASK;
  float* lc = out + OUT_LC;
  float* ssim = out + OUT_SSIM;

  k_transpose<<<3840, 256, 0, stream>>>(feat1, feat2, f1t, f2t);
  k_fold<<<kNL * 128, 128, 0, stream>>>(sa_in_w, sa_in_b, sa_out_w, sa_out_b, sa_ln_g, sa_ln_b,
                                        ca_in_w, ca_in_b, ca_ln_g, ca_ln_b, ca_out_w, wts);
  dim3 g1(1920, 64);
  k_warp<<<g1, 256, 0, stream>>>(f2t, coords, F2, mu, sig, mask);
  k_ssim<<<g1, 256, 0, stream>>>(f1t, F2, mu, sig, ssim);
  k_argmin<<<30, 256, 0, stream>>>(ssim, lc);
  k_attn<<<kP, 64, 0, stream>>>(F2, f1t, wts, ca_out_b, att);
}